// Round 4
// baseline (1062.522 us; speedup 1.0000x reference)
//
#include <hip/hip_runtime.h>
#include <hip/hip_bf16.h>

#define Bb 128
#define Tt 1024
#define Nn 128
#define Ss 256
#define NEGF (-1e30f)
#define D9 9.0f   // fixed log-domain shift per active step (absorbed into c at the end)

typedef __attribute__((ext_vector_type(8))) short short8;  // 8 bf16 (4 VGPRs) — MFMA A/B frag
typedef __attribute__((ext_vector_type(4))) float f32x4;   // MFMA C/D frag

__device__ __forceinline__ short bf16b(float f) {
    __hip_bfloat16 h = __float2bfloat16(f);
    return *reinterpret_cast<short*>(&h);
}

// blocks 0..7:  FCC, 16 batches each, MFMA 16x16x32_bf16, E in registers
// blocks 8..39: FAC, 4 batches each (1 wave per batch, wave-synchronous)
__global__ __launch_bounds__(256) void asg_main(
    const float* __restrict__ trans, const float* __restrict__ x,
    const int* __restrict__ targets, const int* __restrict__ ilen,
    const int* __restrict__ tlen,
    float* __restrict__ fcc_out, float* __restrict__ fac_out)
{
    // u_t double buffer, bf16, [buf][g][j] with j-stride 136 (pad 8; 272 B = 16*17 keeps 16B align)
    __shared__ __align__(16) short ut[2][16][136];
    __shared__ float wred[4][16];

    const int tid  = threadIdx.x;
    const int q    = tid >> 6;      // wave id
    const int lane = tid & 63;
    const int g    = lane & 15;     // batch-in-group (B frag col / D frag col)
    const int quad = lane >> 4;

    if (blockIdx.x < 8) {
        // ================= FCC =================
        const int b   = (blockIdx.x << 4) + g;
        const int len = ilen[b];
        const float* xb = x + (size_t)b * Tt * Nn;

        // E A-fragments: wave q owns rows [32q, 32q+32) -> 2 M-tiles of 16.
        // A[m=lane&15][k=quad*8+jj] per K-chunk kc (K=32 each).
        short8 ea[2][4];
        #pragma unroll
        for (int mt = 0; mt < 2; ++mt) {
            const float* tr = trans + (size_t)(32 * q + 16 * mt + g) * Nn + quad * 8;
            #pragma unroll
            for (int kc = 0; kc < 4; ++kc) {
                short8 v;
                #pragma unroll
                for (int jj = 0; jj < 8; ++jj)
                    v[jj] = bf16b(__expf(tr[kc * 32 + jj]));
                ea[mt][kc] = v;
            }
        }

        const int j0_ = 32 * q + 4 * quad;   // D-layout row base (mt=1 adds 16)

        // u0 = exp(x[0]) (c = 0)
        float uprev[2][4];
        #pragma unroll
        for (int mt = 0; mt < 2; ++mt) {
            const int j0 = j0_ + 16 * mt;
            float4 xv = *(const float4*)(xb + j0);
            uprev[mt][0] = __expf(xv.x); uprev[mt][1] = __expf(xv.y);
            uprev[mt][2] = __expf(xv.z); uprev[mt][3] = __expf(xv.w);
            short4 s4;
            s4.x = bf16b(uprev[mt][0]); s4.y = bf16b(uprev[mt][1]);
            s4.z = bf16b(uprev[mt][2]); s4.w = bf16b(uprev[mt][3]);
            *reinterpret_cast<short4*>(&ut[0][g][j0]) = s4;
        }

        // wc = exp(x[1]-D9) for step 1.
        // x-ring DEPTH 4: xs[k&3][mt] holds x[k]; at step t consume k=t+1, refill k=t+5.
        // Load->use distance = 4 steps (~2000 cyc) > HBM latency (~900 cyc).  [R3 fix]
        float wc[2][4];
        float4 xs[4][2];
        #pragma unroll
        for (int mt = 0; mt < 2; ++mt) {
            const int j0 = j0_ + 16 * mt;
            float4 xv = *(const float4*)(xb + Nn + j0);
            wc[mt][0] = __expf(xv.x - D9); wc[mt][1] = __expf(xv.y - D9);
            wc[mt][2] = __expf(xv.z - D9); wc[mt][3] = __expf(xv.w - D9);
            #pragma unroll
            for (int k = 2; k <= 5; ++k)
                xs[k & 3][mt] = *(const float4*)(xb + (size_t)k * Nn + j0);
        }
        float c = 0.0f;
        __syncthreads();

        for (int t = 1; t < Tt; ++t) {
            // renorm apply (max measured at t-1, t-1 ≡ 7 mod 8)
            if ((t & 7) == 0) {
                float m = fmaxf(fmaxf(wred[0][g], wred[1][g]),
                                fmaxf(wred[2][g], wred[3][g]));
                if (t < len) {
                    float invm = 1.0f / m;
                    #pragma unroll
                    for (int mt = 0; mt < 2; ++mt)
                        #pragma unroll
                        for (int r = 0; r < 4; ++r) wc[mt][r] *= invm;
                    c += __logf(m);
                }
            }

            // B-frags: u_{t-1}[g][k], k = kc*32 + quad*8 + jj  (same k-map as A)
            const short* up = &ut[(t - 1) & 1][g][0] + quad * 8;
            short8 bf0 = *(const short8*)(up);
            short8 bf1 = *(const short8*)(up + 32);
            short8 bf2 = *(const short8*)(up + 64);
            short8 bf3 = *(const short8*)(up + 96);

            // ring refill issued early so the VMEM op overlaps MFMA/LDS work
            const int sl = (t + 1) & 3;
            float4 xnew[2];
            {
                int kk = t + 5; if (kk > Tt - 1) kk = Tt - 1;
                #pragma unroll
                for (int mt = 0; mt < 2; ++mt)
                    xnew[mt] = *(const float4*)(xb + (size_t)kk * Nn + j0_ + 16 * mt);
            }

            f32x4 a0 = {0.f, 0.f, 0.f, 0.f}, a1 = {0.f, 0.f, 0.f, 0.f};
            a0 = __builtin_amdgcn_mfma_f32_16x16x32_bf16(ea[0][0], bf0, a0, 0, 0, 0);
            a1 = __builtin_amdgcn_mfma_f32_16x16x32_bf16(ea[1][0], bf0, a1, 0, 0, 0);
            a0 = __builtin_amdgcn_mfma_f32_16x16x32_bf16(ea[0][1], bf1, a0, 0, 0, 0);
            a1 = __builtin_amdgcn_mfma_f32_16x16x32_bf16(ea[1][1], bf1, a1, 0, 0, 0);
            a0 = __builtin_amdgcn_mfma_f32_16x16x32_bf16(ea[0][2], bf2, a0, 0, 0, 0);
            a1 = __builtin_amdgcn_mfma_f32_16x16x32_bf16(ea[1][2], bf2, a1, 0, 0, 0);
            a0 = __builtin_amdgcn_mfma_f32_16x16x32_bf16(ea[0][3], bf3, a0, 0, 0, 0);
            a1 = __builtin_amdgcn_mfma_f32_16x16x32_bf16(ea[1][3], bf3, a1, 0, 0, 0);

            const bool act = (t < len);
            float un[2][4];
            #pragma unroll
            for (int r = 0; r < 4; ++r) {
                un[0][r] = act ? wc[0][r] * a0[r] : uprev[0][r];
                un[1][r] = act ? wc[1][r] * a1[r] : uprev[1][r];
            }
            #pragma unroll
            for (int mt = 0; mt < 2; ++mt) {
                #pragma unroll
                for (int r = 0; r < 4; ++r) uprev[mt][r] = un[mt][r];
                short4 s4;
                s4.x = bf16b(un[mt][0]); s4.y = bf16b(un[mt][1]);
                s4.z = bf16b(un[mt][2]); s4.w = bf16b(un[mt][3]);
                *reinterpret_cast<short4*>(&ut[t & 1][g][j0_ + 16 * mt]) = s4;
            }

            // wc for step t+1 from ring slot (x[t+1], loaded 4 steps ago)
            #pragma unroll
            for (int mt = 0; mt < 2; ++mt) {
                wc[mt][0] = __expf(xs[sl][mt].x - D9);
                wc[mt][1] = __expf(xs[sl][mt].y - D9);
                wc[mt][2] = __expf(xs[sl][mt].z - D9);
                wc[mt][3] = __expf(xs[sl][mt].w - D9);
                xs[sl][mt] = xnew[mt];
            }

            // renorm measure every 8 steps
            if ((t & 7) == 7) {
                float mm = un[0][0];
                mm = fmaxf(mm, un[0][1]); mm = fmaxf(mm, un[0][2]); mm = fmaxf(mm, un[0][3]);
                mm = fmaxf(mm, un[1][0]); mm = fmaxf(mm, un[1][1]);
                mm = fmaxf(mm, un[1][2]); mm = fmaxf(mm, un[1][3]);
                mm = fmaxf(mm, __shfl_xor(mm, 16));
                mm = fmaxf(mm, __shfl_xor(mm, 32));
                if (lane < 16) wred[q][lane] = mm;
            }
            __syncthreads();
        }

        // every ACTIVE step multiplies u by exp(-D9); absorb into c once.
        c += D9 * (float)(len - 1);

        // fcc = c + log(sum_j u[j][g])
        float s = 0.f;
        #pragma unroll
        for (int mt = 0; mt < 2; ++mt)
            #pragma unroll
            for (int r = 0; r < 4; ++r) s += uprev[mt][r];
        s += __shfl_xor(s, 16);
        s += __shfl_xor(s, 32);
        if (lane < 16) wred[q][lane] = s;
        __syncthreads();
        if (tid < 16) {
            float tot = wred[0][tid] + wred[1][tid] + wred[2][tid] + wred[3][tid];
            fcc_out[(blockIdx.x << 4) + tid] = c + __logf(tot);
        }
    } else {
        // ================= FAC (1 wave per batch, no barriers) =================
        const int b   = ((blockIdx.x - 8) << 2) + q;
        const int len = ilen[b];
        const int tl  = tlen[b];
        const float* xb = x + (size_t)b * Tt * Nn;

        int   tgi[4];
        float st[4], ntr[4], bt[4];
        #pragma unroll
        for (int r = 0; r < 4; ++r) {
            const int s = (lane << 2) + r;
            const int tgv = targets[b * Ss + s];
            const int pg  = (s == 0) ? tgv : targets[b * Ss + s - 1];
            tgi[r] = tgv;
            st[r]  = trans[tgv * Nn + tgv];
            ntr[r] = trans[tgv * Nn + pg];
            bt[r]  = (s == 0) ? xb[tgv] : NEGF;
        }
        // em ring, DEPTH 8 (load->use distance 8 steps to cover HBM latency)
        float em[8][4];
        #pragma unroll
        for (int k = 1; k <= 8; ++k) {
            int tt = k; if (tt > Tt - 1) tt = Tt - 1;
            #pragma unroll
            for (int r = 0; r < 4; ++r) em[(k - 1) & 7][r] = xb[(size_t)tt * Nn + tgi[r]];
        }

        for (int t = 1; t < Tt; ++t) {
            const int d = (t - 1) & 7;
            float bup = __shfl_up(bt[3], 1);
            float prev0 = (lane == 0) ? NEGF : bup;
            float nb[4];
            #pragma unroll
            for (int r = 0; r < 4; ++r) {
                float prev = (r == 0) ? prev0 : bt[r - 1];
                float aa = bt[r] + st[r];
                float bb = prev + ntr[r];
                float hi = fmaxf(aa, bb), lo = fminf(aa, bb);
                nb[r] = em[d][r] + hi + __logf(1.0f + __expf(lo - hi));
            }
            if (t < len) {
                #pragma unroll
                for (int r = 0; r < 4; ++r) bt[r] = nb[r];
            }
            int tn = t + 8; if (tn > Tt - 1) tn = Tt - 1;
            #pragma unroll
            for (int r = 0; r < 4; ++r) em[d][r] = xb[(size_t)tn * Nn + tgi[r]];
        }
        #pragma unroll
        for (int r = 0; r < 4; ++r)
            if ((lane << 2) + r == tl - 1) fac_out[b] = bt[r];
    }
}

__global__ __launch_bounds__(128) void reduce_kernel(const float* __restrict__ fcc,
                                                     const float* __restrict__ fac,
                                                     float* __restrict__ out) {
    __shared__ float r2[2];
    int tid = threadIdx.x;
    float v = fcc[tid] - fac[tid];
    #pragma unroll
    for (int o = 32; o > 0; o >>= 1) v += __shfl_xor(v, o);
    if ((tid & 63) == 0) r2[tid >> 6] = v;
    __syncthreads();
    if (tid == 0) out[0] = (r2[0] + r2[1]) * (1.0f / Bb);
}

extern "C" void kernel_launch(void* const* d_in, const int* in_sizes, int n_in,
                              void* d_out, int out_size, void* d_ws, size_t ws_size,
                              hipStream_t stream) {
    const float* trans   = (const float*)d_in[0];
    const float* x       = (const float*)d_in[1];
    const int*   targets = (const int*)d_in[2];
    const int*   ilen    = (const int*)d_in[3];
    const int*   tlen    = (const int*)d_in[4];
    float* out = (float*)d_out;

    float* fcc = (float*)d_ws;       // B floats
    float* fac = fcc + Bb;           // B floats

    asg_main<<<8 + Bb / 4, 256, 0, stream>>>(trans, x, targets, ilen, tlen, fcc, fac);
    reduce_kernel<<<1, 128, 0, stream>>>(fcc, fac, out);
}

// Round 5
// 432.689 us; speedup vs baseline: 2.4556x; 2.4556x over previous
//
#include <hip/hip_runtime.h>
#include <hip/hip_bf16.h>

#define Bb 128
#define Tt 1024
#define Nn 128
#define Ss 256
#define NEGF (-1e30f)
#define D9 9.0f   // fixed log-domain shift per active step (absorbed into c at the end)

typedef __attribute__((ext_vector_type(8))) short short8;  // 8 bf16 (4 VGPRs) — MFMA A/B frag
typedef __attribute__((ext_vector_type(4))) float f32x4;   // MFMA C/D frag

__device__ __forceinline__ short bf16b(float f) {
    __hip_bfloat16 h = __float2bfloat16(f);
    return *reinterpret_cast<short*>(&h);
}

// ---- FCC per-step body.  t_ = tb + k_ where tb % 8 == 0 (or prologue t_ = k_),
// so every k_-derived expression below is a compile-time constant inside a
// fully-unrolled inner loop — NO dynamically-indexed register arrays (R4 spill fix).
#define FCC_STEP(t_, k_)                                                       \
    {                                                                          \
        const int t = (t_);                                                    \
        if ((k_) == 0) { /* renorm apply: wred written at k==7, post-barrier */\
            float m = fmaxf(fmaxf(wred[0][g], wred[1][g]),                     \
                            fmaxf(wred[2][g], wred[3][g]));                    \
            if (t < len) {                                                     \
                float invm = 1.0f / m;                                         \
                wc[0][0] *= invm; wc[0][1] *= invm;                            \
                wc[0][2] *= invm; wc[0][3] *= invm;                            \
                wc[1][0] *= invm; wc[1][1] *= invm;                            \
                wc[1][2] *= invm; wc[1][3] *= invm;                            \
                c += __logf(m);                                                \
            }                                                                  \
        }                                                                      \
        const short* up = &ut[(t - 1) & 1][g][0] + quad * 8;                   \
        short8 bf0 = *(const short8*)(up);                                     \
        short8 bf1 = *(const short8*)(up + 32);                                \
        short8 bf2 = *(const short8*)(up + 64);                                \
        short8 bf3 = *(const short8*)(up + 96);                                \
        const int sl = ((k_) + 1) & 3;      /* compile-time ring slot */       \
        int kk = t + 5; if (kk > Tt - 1) kk = Tt - 1;                          \
        float4 xnew0 = *(const float4*)(xb + (size_t)kk * Nn + j0_);           \
        float4 xnew1 = *(const float4*)(xb + (size_t)kk * Nn + j0_ + 16);      \
        f32x4 a0 = {0.f, 0.f, 0.f, 0.f}, a1 = {0.f, 0.f, 0.f, 0.f};            \
        a0 = __builtin_amdgcn_mfma_f32_16x16x32_bf16(ea[0][0], bf0, a0, 0, 0, 0); \
        a1 = __builtin_amdgcn_mfma_f32_16x16x32_bf16(ea[1][0], bf0, a1, 0, 0, 0); \
        a0 = __builtin_amdgcn_mfma_f32_16x16x32_bf16(ea[0][1], bf1, a0, 0, 0, 0); \
        a1 = __builtin_amdgcn_mfma_f32_16x16x32_bf16(ea[1][1], bf1, a1, 0, 0, 0); \
        a0 = __builtin_amdgcn_mfma_f32_16x16x32_bf16(ea[0][2], bf2, a0, 0, 0, 0); \
        a1 = __builtin_amdgcn_mfma_f32_16x16x32_bf16(ea[1][2], bf2, a1, 0, 0, 0); \
        a0 = __builtin_amdgcn_mfma_f32_16x16x32_bf16(ea[0][3], bf3, a0, 0, 0, 0); \
        a1 = __builtin_amdgcn_mfma_f32_16x16x32_bf16(ea[1][3], bf3, a1, 0, 0, 0); \
        const bool act = (t < len);                                            \
        float un[2][4];                                                        \
        un[0][0] = act ? wc[0][0] * a0[0] : uprev[0][0];                       \
        un[0][1] = act ? wc[0][1] * a0[1] : uprev[0][1];                       \
        un[0][2] = act ? wc[0][2] * a0[2] : uprev[0][2];                       \
        un[0][3] = act ? wc[0][3] * a0[3] : uprev[0][3];                       \
        un[1][0] = act ? wc[1][0] * a1[0] : uprev[1][0];                       \
        un[1][1] = act ? wc[1][1] * a1[1] : uprev[1][1];                       \
        un[1][2] = act ? wc[1][2] * a1[2] : uprev[1][2];                       \
        un[1][3] = act ? wc[1][3] * a1[3] : uprev[1][3];                       \
        uprev[0][0] = un[0][0]; uprev[0][1] = un[0][1];                        \
        uprev[0][2] = un[0][2]; uprev[0][3] = un[0][3];                        \
        uprev[1][0] = un[1][0]; uprev[1][1] = un[1][1];                        \
        uprev[1][2] = un[1][2]; uprev[1][3] = un[1][3];                        \
        {                                                                      \
            short4 s4;                                                         \
            s4.x = bf16b(un[0][0]); s4.y = bf16b(un[0][1]);                    \
            s4.z = bf16b(un[0][2]); s4.w = bf16b(un[0][3]);                    \
            *reinterpret_cast<short4*>(&ut[t & 1][g][j0_]) = s4;               \
            s4.x = bf16b(un[1][0]); s4.y = bf16b(un[1][1]);                    \
            s4.z = bf16b(un[1][2]); s4.w = bf16b(un[1][3]);                    \
            *reinterpret_cast<short4*>(&ut[t & 1][g][j0_ + 16]) = s4;          \
        }                                                                      \
        /* wc for step t+1 from ring slot (x[t+1], loaded 4 steps ago) */      \
        wc[0][0] = __expf(xs[sl][0].x - D9);                                   \
        wc[0][1] = __expf(xs[sl][0].y - D9);                                   \
        wc[0][2] = __expf(xs[sl][0].z - D9);                                   \
        wc[0][3] = __expf(xs[sl][0].w - D9);                                   \
        wc[1][0] = __expf(xs[sl][1].x - D9);                                   \
        wc[1][1] = __expf(xs[sl][1].y - D9);                                   \
        wc[1][2] = __expf(xs[sl][1].z - D9);                                   \
        wc[1][3] = __expf(xs[sl][1].w - D9);                                   \
        xs[sl][0] = xnew0; xs[sl][1] = xnew1;                                  \
        if ((k_) == 7) { /* renorm measure */                                  \
            float mm = un[0][0];                                               \
            mm = fmaxf(mm, un[0][1]); mm = fmaxf(mm, un[0][2]);                \
            mm = fmaxf(mm, un[0][3]); mm = fmaxf(mm, un[1][0]);                \
            mm = fmaxf(mm, un[1][1]); mm = fmaxf(mm, un[1][2]);                \
            mm = fmaxf(mm, un[1][3]);                                          \
            mm = fmaxf(mm, __shfl_xor(mm, 16));                                \
            mm = fmaxf(mm, __shfl_xor(mm, 32));                                \
            if (lane < 16) wred[q][lane] = mm;                                 \
        }                                                                      \
        __syncthreads();                                                       \
    }

// ---- FAC per-step body; d = (t-1)&7 folded to ((k_)+7)&7 (compile-time).
#define FAC_STEP(t_, k_)                                                       \
    {                                                                          \
        const int t = (t_);                                                    \
        const int d = ((k_) + 7) & 7;                                          \
        float e0 = em[d][0], e1 = em[d][1], e2 = em[d][2], e3 = em[d][3];      \
        int tn = t + 8; if (tn > Tt - 1) tn = Tt - 1;                          \
        const float* xrow = xb + (size_t)tn * Nn;                              \
        em[d][0] = xrow[tgi[0]]; em[d][1] = xrow[tgi[1]];                      \
        em[d][2] = xrow[tgi[2]]; em[d][3] = xrow[tgi[3]];                      \
        float bup = __shfl_up(bt[3], 1);                                       \
        float prev0 = (lane == 0) ? NEGF : bup;                                \
        float nb[4];                                                           \
        {                                                                      \
            float aa = bt[0] + st[0], bb = prev0 + ntr[0];                     \
            float hi = fmaxf(aa, bb), lo = fminf(aa, bb);                      \
            nb[0] = e0 + hi + __logf(1.0f + __expf(lo - hi));                  \
        }                                                                      \
        {                                                                      \
            float aa = bt[1] + st[1], bb = bt[0] + ntr[1];                     \
            float hi = fmaxf(aa, bb), lo = fminf(aa, bb);                      \
            nb[1] = e1 + hi + __logf(1.0f + __expf(lo - hi));                  \
        }                                                                      \
        {                                                                      \
            float aa = bt[2] + st[2], bb = bt[1] + ntr[2];                     \
            float hi = fmaxf(aa, bb), lo = fminf(aa, bb);                      \
            nb[2] = e2 + hi + __logf(1.0f + __expf(lo - hi));                  \
        }                                                                      \
        {                                                                      \
            float aa = bt[3] + st[3], bb = bt[2] + ntr[3];                     \
            float hi = fmaxf(aa, bb), lo = fminf(aa, bb);                      \
            nb[3] = e3 + hi + __logf(1.0f + __expf(lo - hi));                  \
        }                                                                      \
        if (t < len) {                                                         \
            bt[0] = nb[0]; bt[1] = nb[1]; bt[2] = nb[2]; bt[3] = nb[3];        \
        }                                                                      \
    }

// blocks 0..7:  FCC, 16 batches each, MFMA 16x16x32_bf16, E in registers
// blocks 8..39: FAC, 4 batches each (1 wave per batch, wave-synchronous)
__global__ __launch_bounds__(256) void asg_main(
    const float* __restrict__ trans, const float* __restrict__ x,
    const int* __restrict__ targets, const int* __restrict__ ilen,
    const int* __restrict__ tlen,
    float* __restrict__ fcc_out, float* __restrict__ fac_out)
{
    __shared__ __align__(16) short ut[2][16][136];  // pad 8: 272 B row keeps 16B align
    __shared__ float wred[4][16];

    const int tid  = threadIdx.x;
    const int q    = tid >> 6;
    const int lane = tid & 63;
    const int g    = lane & 15;     // batch-in-group (B frag col / D frag col)
    const int quad = lane >> 4;

    if (blockIdx.x < 8) {
        // ================= FCC =================
        const int b   = (blockIdx.x << 4) + g;
        const int len = ilen[b];
        const float* xb = x + (size_t)b * Tt * Nn;

        // E A-fragments: wave q owns rows [32q, 32q+32) -> 2 M-tiles of 16.
        short8 ea[2][4];
        #pragma unroll
        for (int mt = 0; mt < 2; ++mt) {
            const float* tr = trans + (size_t)(32 * q + 16 * mt + g) * Nn + quad * 8;
            #pragma unroll
            for (int kc = 0; kc < 4; ++kc) {
                short8 v;
                #pragma unroll
                for (int jj = 0; jj < 8; ++jj)
                    v[jj] = bf16b(__expf(tr[kc * 32 + jj]));
                ea[mt][kc] = v;
            }
        }

        const int j0_ = 32 * q + 4 * quad;

        // u0 = exp(x[0]) (c = 0)
        float uprev[2][4];
        #pragma unroll
        for (int mt = 0; mt < 2; ++mt) {
            const int j0 = j0_ + 16 * mt;
            float4 xv = *(const float4*)(xb + j0);
            uprev[mt][0] = __expf(xv.x); uprev[mt][1] = __expf(xv.y);
            uprev[mt][2] = __expf(xv.z); uprev[mt][3] = __expf(xv.w);
            short4 s4;
            s4.x = bf16b(uprev[mt][0]); s4.y = bf16b(uprev[mt][1]);
            s4.z = bf16b(uprev[mt][2]); s4.w = bf16b(uprev[mt][3]);
            *reinterpret_cast<short4*>(&ut[0][g][j0]) = s4;
        }

        // wc = exp(x[1]-D9); ring xs[k&3] holds x[k], k=2..5 (depth 4:
        // load->use distance ~4 steps > HBM latency). All indices constant.
        float wc[2][4];
        float4 xs[4][2];
        #pragma unroll
        for (int mt = 0; mt < 2; ++mt) {
            const int j0 = j0_ + 16 * mt;
            float4 xv = *(const float4*)(xb + Nn + j0);
            wc[mt][0] = __expf(xv.x - D9); wc[mt][1] = __expf(xv.y - D9);
            wc[mt][2] = __expf(xv.z - D9); wc[mt][3] = __expf(xv.w - D9);
            #pragma unroll
            for (int k = 2; k <= 5; ++k)
                xs[k & 3][mt] = *(const float4*)(xb + (size_t)k * Nn + j0);
        }
        float c = 0.0f;
        __syncthreads();

        // prologue t = 1..7 (k_ = t, compile-time in unrolled loop)
        #pragma unroll
        for (int k = 1; k < 8; ++k) FCC_STEP(k, k)
        // 127 chunks of 8: t = 8..1023
        for (int tb = 8; tb < Tt; tb += 8) {
            #pragma unroll
            for (int k = 0; k < 8; ++k) FCC_STEP(tb + k, k)
        }

        // every ACTIVE step multiplies u by exp(-D9); absorb into c once.
        c += D9 * (float)(len - 1);

        float s = 0.f;
        #pragma unroll
        for (int mt = 0; mt < 2; ++mt)
            #pragma unroll
            for (int r = 0; r < 4; ++r) s += uprev[mt][r];
        s += __shfl_xor(s, 16);
        s += __shfl_xor(s, 32);
        if (lane < 16) wred[q][lane] = s;
        __syncthreads();
        if (tid < 16) {
            float tot = wred[0][tid] + wred[1][tid] + wred[2][tid] + wred[3][tid];
            fcc_out[(blockIdx.x << 4) + tid] = c + __logf(tot);
        }
    } else {
        // ================= FAC (1 wave per batch, no barriers) =================
        const int b   = ((blockIdx.x - 8) << 2) + q;
        const int len = ilen[b];
        const int tl  = tlen[b];
        const float* xb = x + (size_t)b * Tt * Nn;

        int   tgi[4];
        float st[4], ntr[4], bt[4];
        #pragma unroll
        for (int r = 0; r < 4; ++r) {
            const int s = (lane << 2) + r;
            const int tgv = targets[b * Ss + s];
            const int pg  = (s == 0) ? tgv : targets[b * Ss + s - 1];
            tgi[r] = tgv;
            st[r]  = trans[tgv * Nn + tgv];
            ntr[r] = trans[tgv * Nn + pg];
            bt[r]  = (s == 0) ? xb[tgv] : NEGF;
        }
        // em ring depth 8; em[(k-1)&7] = x[k] for k=1..8 (constant indices)
        float em[8][4];
        #pragma unroll
        for (int k = 1; k <= 8; ++k) {
            int tt = k; if (tt > Tt - 1) tt = Tt - 1;
            const float* xrow = xb + (size_t)tt * Nn;
            em[(k - 1) & 7][0] = xrow[tgi[0]];
            em[(k - 1) & 7][1] = xrow[tgi[1]];
            em[(k - 1) & 7][2] = xrow[tgi[2]];
            em[(k - 1) & 7][3] = xrow[tgi[3]];
        }

        #pragma unroll
        for (int k = 1; k < 8; ++k) FAC_STEP(k, k)
        for (int tb = 8; tb < Tt; tb += 8) {
            #pragma unroll
            for (int k = 0; k < 8; ++k) FAC_STEP(tb + k, k)
        }

        #pragma unroll
        for (int r = 0; r < 4; ++r)
            if ((lane << 2) + r == tl - 1) fac_out[b] = bt[r];
    }
}

__global__ __launch_bounds__(128) void reduce_kernel(const float* __restrict__ fcc,
                                                     const float* __restrict__ fac,
                                                     float* __restrict__ out) {
    __shared__ float r2[2];
    int tid = threadIdx.x;
    float v = fcc[tid] - fac[tid];
    #pragma unroll
    for (int o = 32; o > 0; o >>= 1) v += __shfl_xor(v, o);
    if ((tid & 63) == 0) r2[tid >> 6] = v;
    __syncthreads();
    if (tid == 0) out[0] = (r2[0] + r2[1]) * (1.0f / Bb);
}

extern "C" void kernel_launch(void* const* d_in, const int* in_sizes, int n_in,
                              void* d_out, int out_size, void* d_ws, size_t ws_size,
                              hipStream_t stream) {
    const float* trans   = (const float*)d_in[0];
    const float* x       = (const float*)d_in[1];
    const int*   targets = (const int*)d_in[2];
    const int*   ilen    = (const int*)d_in[3];
    const int*   tlen    = (const int*)d_in[4];
    float* out = (float*)d_out;

    float* fcc = (float*)d_ws;       // B floats
    float* fac = fcc + Bb;           // B floats

    asg_main<<<8 + Bb / 4, 256, 0, stream>>>(trans, x, targets, ilen, tlen, fcc, fac);
    reduce_kernel<<<1, 128, 0, stream>>>(fcc, fac, out);
}

// Round 6
// 392.234 us; speedup vs baseline: 2.7089x; 1.1031x over previous
//
#include <hip/hip_runtime.h>
#include <hip/hip_bf16.h>

#define Bb 128
#define Tt 1024
#define Nn 128
#define Ss 256
#define NEGF (-1e30f)
#define D9 9.0f   // fixed log-domain shift per active step (absorbed into c at the end)

typedef __attribute__((ext_vector_type(8))) short short8;  // 8 bf16 (4 VGPRs) — MFMA A/B frag
typedef __attribute__((ext_vector_type(4))) float f32x4;   // MFMA C/D frag

__device__ __forceinline__ short bf16b(float f) {
    __hip_bfloat16 h = __float2bfloat16(f);
    return *reinterpret_cast<short*>(&h);
}

// ---- FCC per-step body.  t_ = tb + k_ (tb%8==0), k_ compile-time -> all ring
// indices fold to constants (R4 spill fix).  R5->R6: refill loads write the
// ring slot DIRECTLY (no same-step register copy -> no same-step vmcnt wait;
// first use of loaded regs is 4 steps later, covering ~900cyc HBM latency).
// Accumulator chains split 4-deep -> 2x2-deep + final add.
#define FCC_STEP(t_, k_)                                                       \
    {                                                                          \
        const int t = (t_);                                                    \
        if ((k_) == 0) { /* renorm apply: wred written at k==7, post-barrier */\
            float m = fmaxf(fmaxf(wred[0][g], wred[1][g]),                     \
                            fmaxf(wred[2][g], wred[3][g]));                    \
            if (t < len) {                                                     \
                float invm = 1.0f / m;                                         \
                wc[0][0] *= invm; wc[0][1] *= invm;                            \
                wc[0][2] *= invm; wc[0][3] *= invm;                            \
                wc[1][0] *= invm; wc[1][1] *= invm;                            \
                wc[1][2] *= invm; wc[1][3] *= invm;                            \
                c += __logf(m);                                                \
            }                                                                  \
        }                                                                      \
        const short* up = &ut[(t - 1) & 1][g][0] + quad * 8;                   \
        short8 bf0 = *(const short8*)(up);                                     \
        short8 bf1 = *(const short8*)(up + 32);                                \
        short8 bf2 = *(const short8*)(up + 64);                                \
        short8 bf3 = *(const short8*)(up + 96);                                \
        f32x4 a0p = {0.f, 0.f, 0.f, 0.f}, a0q = {0.f, 0.f, 0.f, 0.f};          \
        f32x4 a1p = {0.f, 0.f, 0.f, 0.f}, a1q = {0.f, 0.f, 0.f, 0.f};          \
        a0p = __builtin_amdgcn_mfma_f32_16x16x32_bf16(ea[0][0], bf0, a0p, 0, 0, 0); \
        a1p = __builtin_amdgcn_mfma_f32_16x16x32_bf16(ea[1][0], bf0, a1p, 0, 0, 0); \
        a0q = __builtin_amdgcn_mfma_f32_16x16x32_bf16(ea[0][2], bf2, a0q, 0, 0, 0); \
        a1q = __builtin_amdgcn_mfma_f32_16x16x32_bf16(ea[1][2], bf2, a1q, 0, 0, 0); \
        a0p = __builtin_amdgcn_mfma_f32_16x16x32_bf16(ea[0][1], bf1, a0p, 0, 0, 0); \
        a1p = __builtin_amdgcn_mfma_f32_16x16x32_bf16(ea[1][1], bf1, a1p, 0, 0, 0); \
        a0q = __builtin_amdgcn_mfma_f32_16x16x32_bf16(ea[0][3], bf3, a0q, 0, 0, 0); \
        a1q = __builtin_amdgcn_mfma_f32_16x16x32_bf16(ea[1][3], bf3, a1q, 0, 0, 0); \
        const bool act = (t < len);                                            \
        float un[2][4];                                                        \
        un[0][0] = act ? wc[0][0] * (a0p[0] + a0q[0]) : uprev[0][0];           \
        un[0][1] = act ? wc[0][1] * (a0p[1] + a0q[1]) : uprev[0][1];           \
        un[0][2] = act ? wc[0][2] * (a0p[2] + a0q[2]) : uprev[0][2];           \
        un[0][3] = act ? wc[0][3] * (a0p[3] + a0q[3]) : uprev[0][3];           \
        un[1][0] = act ? wc[1][0] * (a1p[0] + a1q[0]) : uprev[1][0];           \
        un[1][1] = act ? wc[1][1] * (a1p[1] + a1q[1]) : uprev[1][1];           \
        un[1][2] = act ? wc[1][2] * (a1p[2] + a1q[2]) : uprev[1][2];           \
        un[1][3] = act ? wc[1][3] * (a1p[3] + a1q[3]) : uprev[1][3];           \
        uprev[0][0] = un[0][0]; uprev[0][1] = un[0][1];                        \
        uprev[0][2] = un[0][2]; uprev[0][3] = un[0][3];                        \
        uprev[1][0] = un[1][0]; uprev[1][1] = un[1][1];                        \
        uprev[1][2] = un[1][2]; uprev[1][3] = un[1][3];                        \
        {                                                                      \
            short4 s4;                                                         \
            s4.x = bf16b(un[0][0]); s4.y = bf16b(un[0][1]);                    \
            s4.z = bf16b(un[0][2]); s4.w = bf16b(un[0][3]);                    \
            *reinterpret_cast<short4*>(&ut[t & 1][g][j0_]) = s4;               \
            s4.x = bf16b(un[1][0]); s4.y = bf16b(un[1][1]);                    \
            s4.z = bf16b(un[1][2]); s4.w = bf16b(un[1][3]);                    \
            *reinterpret_cast<short4*>(&ut[t & 1][g][j0_ + 16]) = s4;          \
        }                                                                      \
        /* consume ring slot (x[t+1], loaded 4 steps ago) into wc ... */       \
        const int sl = ((k_) + 1) & 3;                                         \
        wc[0][0] = __expf(xs[sl][0].x - D9);                                   \
        wc[0][1] = __expf(xs[sl][0].y - D9);                                   \
        wc[0][2] = __expf(xs[sl][0].z - D9);                                   \
        wc[0][3] = __expf(xs[sl][0].w - D9);                                   \
        wc[1][0] = __expf(xs[sl][1].x - D9);                                   \
        wc[1][1] = __expf(xs[sl][1].y - D9);                                   \
        wc[1][2] = __expf(xs[sl][1].z - D9);                                   \
        wc[1][3] = __expf(xs[sl][1].w - D9);                                   \
        /* ... then refill the SAME slot directly from global (x[t+5]); */     \
        /* these registers are next touched 4 steps from now. */               \
        {                                                                      \
            int kk = t + 5; if (kk > Tt - 1) kk = Tt - 1;                      \
            xs[sl][0] = *(const float4*)(xb + (size_t)kk * Nn + j0_);          \
            xs[sl][1] = *(const float4*)(xb + (size_t)kk * Nn + j0_ + 16);     \
        }                                                                      \
        if ((k_) == 7) { /* renorm measure */                                  \
            float mm = un[0][0];                                               \
            mm = fmaxf(mm, un[0][1]); mm = fmaxf(mm, un[0][2]);                \
            mm = fmaxf(mm, un[0][3]); mm = fmaxf(mm, un[1][0]);                \
            mm = fmaxf(mm, un[1][1]); mm = fmaxf(mm, un[1][2]);                \
            mm = fmaxf(mm, un[1][3]);                                          \
            mm = fmaxf(mm, __shfl_xor(mm, 16));                                \
            mm = fmaxf(mm, __shfl_xor(mm, 32));                                \
            if (lane < 16) wred[q][lane] = mm;                                 \
        }                                                                      \
        __syncthreads();                                                       \
    }

// ---- FAC per-step body; d = ((k_)+7)&7 compile-time; em refilled by direct load.
#define FAC_STEP(t_, k_)                                                       \
    {                                                                          \
        const int t = (t_);                                                    \
        const int d = ((k_) + 7) & 7;                                          \
        float e0 = em[d][0], e1 = em[d][1], e2 = em[d][2], e3 = em[d][3];      \
        int tn = t + 8; if (tn > Tt - 1) tn = Tt - 1;                          \
        const float* xrow = xb + (size_t)tn * Nn;                              \
        em[d][0] = xrow[tgi[0]]; em[d][1] = xrow[tgi[1]];                      \
        em[d][2] = xrow[tgi[2]]; em[d][3] = xrow[tgi[3]];                      \
        float bup = __shfl_up(bt[3], 1);                                       \
        float prev0 = (lane == 0) ? NEGF : bup;                                \
        float nb[4];                                                           \
        {                                                                      \
            float aa = bt[0] + st[0], bb = prev0 + ntr[0];                     \
            float hi = fmaxf(aa, bb), lo = fminf(aa, bb);                      \
            nb[0] = e0 + hi + __logf(1.0f + __expf(lo - hi));                  \
        }                                                                      \
        {                                                                      \
            float aa = bt[1] + st[1], bb = bt[0] + ntr[1];                     \
            float hi = fmaxf(aa, bb), lo = fminf(aa, bb);                      \
            nb[1] = e1 + hi + __logf(1.0f + __expf(lo - hi));                  \
        }                                                                      \
        {                                                                      \
            float aa = bt[2] + st[2], bb = bt[1] + ntr[2];                     \
            float hi = fmaxf(aa, bb), lo = fminf(aa, bb);                      \
            nb[2] = e2 + hi + __logf(1.0f + __expf(lo - hi));                  \
        }                                                                      \
        {                                                                      \
            float aa = bt[3] + st[3], bb = bt[2] + ntr[3];                     \
            float hi = fmaxf(aa, bb), lo = fminf(aa, bb);                      \
            nb[3] = e3 + hi + __logf(1.0f + __expf(lo - hi));                  \
        }                                                                      \
        if (t < len) {                                                         \
            bt[0] = nb[0]; bt[1] = nb[1]; bt[2] = nb[2]; bt[3] = nb[3];        \
        }                                                                      \
    }

// blocks 0..7:  FCC, 16 batches each, MFMA 16x16x32_bf16, E in registers
// blocks 8..39: FAC, 4 batches each (1 wave per batch, wave-synchronous)
__global__ __launch_bounds__(256) void asg_main(
    const float* __restrict__ trans, const float* __restrict__ x,
    const int* __restrict__ targets, const int* __restrict__ ilen,
    const int* __restrict__ tlen,
    float* __restrict__ fcc_out, float* __restrict__ fac_out)
{
    __shared__ __align__(16) short ut[2][16][136];  // pad 8: 272 B row keeps 16B align
    __shared__ float wred[4][16];

    const int tid  = threadIdx.x;
    const int q    = tid >> 6;
    const int lane = tid & 63;
    const int g    = lane & 15;     // batch-in-group (B frag col / D frag col)
    const int quad = lane >> 4;

    if (blockIdx.x < 8) {
        // ================= FCC =================
        const int b   = (blockIdx.x << 4) + g;
        const int len = ilen[b];
        const float* xb = x + (size_t)b * Tt * Nn;

        // E A-fragments: wave q owns rows [32q, 32q+32) -> 2 M-tiles of 16.
        short8 ea[2][4];
        #pragma unroll
        for (int mt = 0; mt < 2; ++mt) {
            const float* tr = trans + (size_t)(32 * q + 16 * mt + g) * Nn + quad * 8;
            #pragma unroll
            for (int kc = 0; kc < 4; ++kc) {
                short8 v;
                #pragma unroll
                for (int jj = 0; jj < 8; ++jj)
                    v[jj] = bf16b(__expf(tr[kc * 32 + jj]));
                ea[mt][kc] = v;
            }
        }

        const int j0_ = 32 * q + 4 * quad;

        // u0 = exp(x[0]) (c = 0)
        float uprev[2][4];
        #pragma unroll
        for (int mt = 0; mt < 2; ++mt) {
            const int j0 = j0_ + 16 * mt;
            float4 xv = *(const float4*)(xb + j0);
            uprev[mt][0] = __expf(xv.x); uprev[mt][1] = __expf(xv.y);
            uprev[mt][2] = __expf(xv.z); uprev[mt][3] = __expf(xv.w);
            short4 s4;
            s4.x = bf16b(uprev[mt][0]); s4.y = bf16b(uprev[mt][1]);
            s4.z = bf16b(uprev[mt][2]); s4.w = bf16b(uprev[mt][3]);
            *reinterpret_cast<short4*>(&ut[0][g][j0]) = s4;
        }

        // wc = exp(x[1]-D9); ring xs[k&3] holds x[k], k=2..5 (depth 4)
        float wc[2][4];
        float4 xs[4][2];
        #pragma unroll
        for (int mt = 0; mt < 2; ++mt) {
            const int j0 = j0_ + 16 * mt;
            float4 xv = *(const float4*)(xb + Nn + j0);
            wc[mt][0] = __expf(xv.x - D9); wc[mt][1] = __expf(xv.y - D9);
            wc[mt][2] = __expf(xv.z - D9); wc[mt][3] = __expf(xv.w - D9);
            #pragma unroll
            for (int k = 2; k <= 5; ++k)
                xs[k & 3][mt] = *(const float4*)(xb + (size_t)k * Nn + j0);
        }
        float c = 0.0f;
        __syncthreads();

        // prologue t = 1..7 (k_ = t, compile-time in unrolled loop)
        #pragma unroll
        for (int k = 1; k < 8; ++k) FCC_STEP(k, k)
        // 127 chunks of 8: t = 8..1023
        for (int tb = 8; tb < Tt; tb += 8) {
            #pragma unroll
            for (int k = 0; k < 8; ++k) FCC_STEP(tb + k, k)
        }

        // every ACTIVE step multiplies u by exp(-D9); absorb into c once.
        c += D9 * (float)(len - 1);

        float s = 0.f;
        #pragma unroll
        for (int mt = 0; mt < 2; ++mt)
            #pragma unroll
            for (int r = 0; r < 4; ++r) s += uprev[mt][r];
        s += __shfl_xor(s, 16);
        s += __shfl_xor(s, 32);
        if (lane < 16) wred[q][lane] = s;
        __syncthreads();
        if (tid < 16) {
            float tot = wred[0][tid] + wred[1][tid] + wred[2][tid] + wred[3][tid];
            fcc_out[(blockIdx.x << 4) + tid] = c + __logf(tot);
        }
    } else {
        // ================= FAC (1 wave per batch, no barriers) =================
        const int b   = ((blockIdx.x - 8) << 2) + q;
        const int len = ilen[b];
        const int tl  = tlen[b];
        const float* xb = x + (size_t)b * Tt * Nn;

        int   tgi[4];
        float st[4], ntr[4], bt[4];
        #pragma unroll
        for (int r = 0; r < 4; ++r) {
            const int s = (lane << 2) + r;
            const int tgv = targets[b * Ss + s];
            const int pg  = (s == 0) ? tgv : targets[b * Ss + s - 1];
            tgi[r] = tgv;
            st[r]  = trans[tgv * Nn + tgv];
            ntr[r] = trans[tgv * Nn + pg];
            bt[r]  = (s == 0) ? xb[tgv] : NEGF;
        }
        // em ring depth 8; em[(k-1)&7] = x[k] for k=1..8 (constant indices)
        float em[8][4];
        #pragma unroll
        for (int k = 1; k <= 8; ++k) {
            int tt = k; if (tt > Tt - 1) tt = Tt - 1;
            const float* xrow = xb + (size_t)tt * Nn;
            em[(k - 1) & 7][0] = xrow[tgi[0]];
            em[(k - 1) & 7][1] = xrow[tgi[1]];
            em[(k - 1) & 7][2] = xrow[tgi[2]];
            em[(k - 1) & 7][3] = xrow[tgi[3]];
        }

        #pragma unroll
        for (int k = 1; k < 8; ++k) FAC_STEP(k, k)
        for (int tb = 8; tb < Tt; tb += 8) {
            #pragma unroll
            for (int k = 0; k < 8; ++k) FAC_STEP(tb + k, k)
        }

        #pragma unroll
        for (int r = 0; r < 4; ++r)
            if ((lane << 2) + r == tl - 1) fac_out[b] = bt[r];
    }
}

__global__ __launch_bounds__(128) void reduce_kernel(const float* __restrict__ fcc,
                                                     const float* __restrict__ fac,
                                                     float* __restrict__ out) {
    __shared__ float r2[2];
    int tid = threadIdx.x;
    float v = fcc[tid] - fac[tid];
    #pragma unroll
    for (int o = 32; o > 0; o >>= 1) v += __shfl_xor(v, o);
    if ((tid & 63) == 0) r2[tid >> 6] = v;
    __syncthreads();
    if (tid == 0) out[0] = (r2[0] + r2[1]) * (1.0f / Bb);
}

extern "C" void kernel_launch(void* const* d_in, const int* in_sizes, int n_in,
                              void* d_out, int out_size, void* d_ws, size_t ws_size,
                              hipStream_t stream) {
    const float* trans   = (const float*)d_in[0];
    const float* x       = (const float*)d_in[1];
    const int*   targets = (const int*)d_in[2];
    const int*   ilen    = (const int*)d_in[3];
    const int*   tlen    = (const int*)d_in[4];
    float* out = (float*)d_out;

    float* fcc = (float*)d_ws;       // B floats
    float* fac = fcc + Bb;           // B floats

    asg_main<<<8 + Bb / 4, 256, 0, stream>>>(trans, x, targets, ilen, tlen, fcc, fac);
    reduce_kernel<<<1, 128, 0, stream>>>(fcc, fac, out);
}

// Round 7
// 391.824 us; speedup vs baseline: 2.7117x; 1.0010x over previous
//
#include <hip/hip_runtime.h>
#include <hip/hip_bf16.h>

#define Bb 128
#define Tt 1024
#define Nn 128
#define Ss 256
#define NEGF (-1e30f)
#define D9 9.0f   // fixed log-domain shift per active step (absorbed into c at the end)

typedef __attribute__((ext_vector_type(8))) short short8;  // 8 bf16 (4 VGPRs) — MFMA A/B frag
typedef __attribute__((ext_vector_type(4))) float f32x4;   // MFMA C/D frag

__device__ __forceinline__ short bf16b(float f) {
    __hip_bfloat16 h = __float2bfloat16(f);
    return *reinterpret_cast<short*>(&h);
}

// Raw workgroup barrier that drains ONLY LDS (lgkmcnt), not vmcnt.
// __syncthreads() emits s_waitcnt vmcnt(0) lgkmcnt(0) + s_barrier, which
// force-drains the in-flight x prefetch loads every step (m97-style ~450cyc
// stall). Inter-wave ordering here only involves LDS (ut, wred); register
// destinations of global loads need no inter-wave ordering.
#define LDS_BARRIER() asm volatile("s_waitcnt lgkmcnt(0)\n\ts_barrier" ::: "memory")

// ---- FCC per-step body.  t_ = tb + k_ (tb%8==0), k_ compile-time -> all ring
// indices fold to constants (R4 spill fix). Ring slots refilled by DIRECT
// global->register loads (R6), consumed 4 steps later; barriers leave vmcnt
// outstanding (R7).
#define FCC_STEP(t_, k_)                                                       \
    {                                                                          \
        const int t = (t_);                                                    \
        if ((k_) == 0) { /* renorm apply: wred written at k==7, post-barrier */\
            float m = fmaxf(fmaxf(wred[0][g], wred[1][g]),                     \
                            fmaxf(wred[2][g], wred[3][g]));                    \
            if (t < len) {                                                     \
                float invm = 1.0f / m;                                         \
                wc[0][0] *= invm; wc[0][1] *= invm;                            \
                wc[0][2] *= invm; wc[0][3] *= invm;                            \
                wc[1][0] *= invm; wc[1][1] *= invm;                            \
                wc[1][2] *= invm; wc[1][3] *= invm;                            \
                c += __logf(m);                                                \
            }                                                                  \
        }                                                                      \
        const short* up = &ut[(t - 1) & 1][g][0] + quad * 8;                   \
        short8 bf0 = *(const short8*)(up);                                     \
        short8 bf1 = *(const short8*)(up + 32);                                \
        short8 bf2 = *(const short8*)(up + 64);                                \
        short8 bf3 = *(const short8*)(up + 96);                                \
        f32x4 a0p = {0.f, 0.f, 0.f, 0.f}, a0q = {0.f, 0.f, 0.f, 0.f};          \
        f32x4 a1p = {0.f, 0.f, 0.f, 0.f}, a1q = {0.f, 0.f, 0.f, 0.f};          \
        a0p = __builtin_amdgcn_mfma_f32_16x16x32_bf16(ea[0][0], bf0, a0p, 0, 0, 0); \
        a1p = __builtin_amdgcn_mfma_f32_16x16x32_bf16(ea[1][0], bf0, a1p, 0, 0, 0); \
        a0q = __builtin_amdgcn_mfma_f32_16x16x32_bf16(ea[0][2], bf2, a0q, 0, 0, 0); \
        a1q = __builtin_amdgcn_mfma_f32_16x16x32_bf16(ea[1][2], bf2, a1q, 0, 0, 0); \
        a0p = __builtin_amdgcn_mfma_f32_16x16x32_bf16(ea[0][1], bf1, a0p, 0, 0, 0); \
        a1p = __builtin_amdgcn_mfma_f32_16x16x32_bf16(ea[1][1], bf1, a1p, 0, 0, 0); \
        a0q = __builtin_amdgcn_mfma_f32_16x16x32_bf16(ea[0][3], bf3, a0q, 0, 0, 0); \
        a1q = __builtin_amdgcn_mfma_f32_16x16x32_bf16(ea[1][3], bf3, a1q, 0, 0, 0); \
        const bool act = (t < len);                                            \
        float un[2][4];                                                        \
        un[0][0] = act ? wc[0][0] * (a0p[0] + a0q[0]) : uprev[0][0];           \
        un[0][1] = act ? wc[0][1] * (a0p[1] + a0q[1]) : uprev[0][1];           \
        un[0][2] = act ? wc[0][2] * (a0p[2] + a0q[2]) : uprev[0][2];           \
        un[0][3] = act ? wc[0][3] * (a0p[3] + a0q[3]) : uprev[0][3];           \
        un[1][0] = act ? wc[1][0] * (a1p[0] + a1q[0]) : uprev[1][0];           \
        un[1][1] = act ? wc[1][1] * (a1p[1] + a1q[1]) : uprev[1][1];           \
        un[1][2] = act ? wc[1][2] * (a1p[2] + a1q[2]) : uprev[1][2];           \
        un[1][3] = act ? wc[1][3] * (a1p[3] + a1q[3]) : uprev[1][3];           \
        uprev[0][0] = un[0][0]; uprev[0][1] = un[0][1];                        \
        uprev[0][2] = un[0][2]; uprev[0][3] = un[0][3];                        \
        uprev[1][0] = un[1][0]; uprev[1][1] = un[1][1];                        \
        uprev[1][2] = un[1][2]; uprev[1][3] = un[1][3];                        \
        {                                                                      \
            short4 s4;                                                         \
            s4.x = bf16b(un[0][0]); s4.y = bf16b(un[0][1]);                    \
            s4.z = bf16b(un[0][2]); s4.w = bf16b(un[0][3]);                    \
            *reinterpret_cast<short4*>(&ut[t & 1][g][j0_]) = s4;               \
            s4.x = bf16b(un[1][0]); s4.y = bf16b(un[1][1]);                    \
            s4.z = bf16b(un[1][2]); s4.w = bf16b(un[1][3]);                    \
            *reinterpret_cast<short4*>(&ut[t & 1][g][j0_ + 16]) = s4;          \
        }                                                                      \
        /* consume ring slot (x[t+1], loaded 4 steps ago) into wc ... */       \
        const int sl = ((k_) + 1) & 3;                                         \
        wc[0][0] = __expf(xs[sl][0].x - D9);                                   \
        wc[0][1] = __expf(xs[sl][0].y - D9);                                   \
        wc[0][2] = __expf(xs[sl][0].z - D9);                                   \
        wc[0][3] = __expf(xs[sl][0].w - D9);                                   \
        wc[1][0] = __expf(xs[sl][1].x - D9);                                   \
        wc[1][1] = __expf(xs[sl][1].y - D9);                                   \
        wc[1][2] = __expf(xs[sl][1].z - D9);                                   \
        wc[1][3] = __expf(xs[sl][1].w - D9);                                   \
        /* ... then refill the SAME slot directly from global (x[t+5]); */     \
        /* first touch of these registers is 4 steps (~>1600cyc) away. */      \
        {                                                                      \
            int kk = t + 5; if (kk > Tt - 1) kk = Tt - 1;                      \
            xs[sl][0] = *(const float4*)(xb + (size_t)kk * Nn + j0_);          \
            xs[sl][1] = *(const float4*)(xb + (size_t)kk * Nn + j0_ + 16);     \
        }                                                                      \
        if ((k_) == 7) { /* renorm measure */                                  \
            float mm = un[0][0];                                               \
            mm = fmaxf(mm, un[0][1]); mm = fmaxf(mm, un[0][2]);                \
            mm = fmaxf(mm, un[0][3]); mm = fmaxf(mm, un[1][0]);                \
            mm = fmaxf(mm, un[1][1]); mm = fmaxf(mm, un[1][2]);                \
            mm = fmaxf(mm, un[1][3]);                                          \
            mm = fmaxf(mm, __shfl_xor(mm, 16));                                \
            mm = fmaxf(mm, __shfl_xor(mm, 32));                                \
            if (lane < 16) wred[q][lane] = mm;                                 \
        }                                                                      \
        LDS_BARRIER();                                                         \
    }

// ---- FAC per-step body; d = ((k_)+7)&7 compile-time; em refilled by direct load.
#define FAC_STEP(t_, k_)                                                       \
    {                                                                          \
        const int t = (t_);                                                    \
        const int d = ((k_) + 7) & 7;                                          \
        float e0 = em[d][0], e1 = em[d][1], e2 = em[d][2], e3 = em[d][3];      \
        int tn = t + 8; if (tn > Tt - 1) tn = Tt - 1;                          \
        const float* xrow = xb + (size_t)tn * Nn;                              \
        em[d][0] = xrow[tgi[0]]; em[d][1] = xrow[tgi[1]];                      \
        em[d][2] = xrow[tgi[2]]; em[d][3] = xrow[tgi[3]];                      \
        float bup = __shfl_up(bt[3], 1);                                       \
        float prev0 = (lane == 0) ? NEGF : bup;                                \
        float nb[4];                                                           \
        {                                                                      \
            float aa = bt[0] + st[0], bb = prev0 + ntr[0];                     \
            float hi = fmaxf(aa, bb), lo = fminf(aa, bb);                      \
            nb[0] = e0 + hi + __logf(1.0f + __expf(lo - hi));                  \
        }                                                                      \
        {                                                                      \
            float aa = bt[1] + st[1], bb = bt[0] + ntr[1];                     \
            float hi = fmaxf(aa, bb), lo = fminf(aa, bb);                      \
            nb[1] = e1 + hi + __logf(1.0f + __expf(lo - hi));                  \
        }                                                                      \
        {                                                                      \
            float aa = bt[2] + st[2], bb = bt[1] + ntr[2];                     \
            float hi = fmaxf(aa, bb), lo = fminf(aa, bb);                      \
            nb[2] = e2 + hi + __logf(1.0f + __expf(lo - hi));                  \
        }                                                                      \
        {                                                                      \
            float aa = bt[3] + st[3], bb = bt[2] + ntr[3];                     \
            float hi = fmaxf(aa, bb), lo = fminf(aa, bb);                      \
            nb[3] = e3 + hi + __logf(1.0f + __expf(lo - hi));                  \
        }                                                                      \
        if (t < len) {                                                         \
            bt[0] = nb[0]; bt[1] = nb[1]; bt[2] = nb[2]; bt[3] = nb[3];        \
        }                                                                      \
    }

// blocks 0..7:  FCC, 16 batches each, MFMA 16x16x32_bf16, E in registers
// blocks 8..39: FAC, 4 batches each (1 wave per batch, wave-synchronous)
__global__ __launch_bounds__(256) void asg_main(
    const float* __restrict__ trans, const float* __restrict__ x,
    const int* __restrict__ targets, const int* __restrict__ ilen,
    const int* __restrict__ tlen,
    float* __restrict__ fcc_out, float* __restrict__ fac_out)
{
    __shared__ __align__(16) short ut[2][16][136];  // pad 8: 272 B row keeps 16B align
    __shared__ float wred[4][16];

    const int tid  = threadIdx.x;
    const int q    = tid >> 6;
    const int lane = tid & 63;
    const int g    = lane & 15;     // batch-in-group (B frag col / D frag col)
    const int quad = lane >> 4;

    if (blockIdx.x < 8) {
        // ================= FCC =================
        const int b   = (blockIdx.x << 4) + g;
        const int len = ilen[b];
        const float* xb = x + (size_t)b * Tt * Nn;

        // E A-fragments: wave q owns rows [32q, 32q+32) -> 2 M-tiles of 16.
        short8 ea[2][4];
        #pragma unroll
        for (int mt = 0; mt < 2; ++mt) {
            const float* tr = trans + (size_t)(32 * q + 16 * mt + g) * Nn + quad * 8;
            #pragma unroll
            for (int kc = 0; kc < 4; ++kc) {
                short8 v;
                #pragma unroll
                for (int jj = 0; jj < 8; ++jj)
                    v[jj] = bf16b(__expf(tr[kc * 32 + jj]));
                ea[mt][kc] = v;
            }
        }

        const int j0_ = 32 * q + 4 * quad;

        // u0 = exp(x[0]) (c = 0)
        float uprev[2][4];
        #pragma unroll
        for (int mt = 0; mt < 2; ++mt) {
            const int j0 = j0_ + 16 * mt;
            float4 xv = *(const float4*)(xb + j0);
            uprev[mt][0] = __expf(xv.x); uprev[mt][1] = __expf(xv.y);
            uprev[mt][2] = __expf(xv.z); uprev[mt][3] = __expf(xv.w);
            short4 s4;
            s4.x = bf16b(uprev[mt][0]); s4.y = bf16b(uprev[mt][1]);
            s4.z = bf16b(uprev[mt][2]); s4.w = bf16b(uprev[mt][3]);
            *reinterpret_cast<short4*>(&ut[0][g][j0]) = s4;
        }

        // wc = exp(x[1]-D9); ring xs[k&3] holds x[k], k=2..5 (depth 4)
        float wc[2][4];
        float4 xs[4][2];
        #pragma unroll
        for (int mt = 0; mt < 2; ++mt) {
            const int j0 = j0_ + 16 * mt;
            float4 xv = *(const float4*)(xb + Nn + j0);
            wc[mt][0] = __expf(xv.x - D9); wc[mt][1] = __expf(xv.y - D9);
            wc[mt][2] = __expf(xv.z - D9); wc[mt][3] = __expf(xv.w - D9);
            #pragma unroll
            for (int k = 2; k <= 5; ++k)
                xs[k & 3][mt] = *(const float4*)(xb + (size_t)k * Nn + j0);
        }
        float c = 0.0f;
        __syncthreads();   // setup barrier (once; full drain acceptable)

        // prologue t = 1..7 (k_ = t, compile-time in unrolled loop)
        #pragma unroll
        for (int k = 1; k < 8; ++k) FCC_STEP(k, k)
        // 127 chunks of 8: t = 8..1023
        for (int tb = 8; tb < Tt; tb += 8) {
            #pragma unroll
            for (int k = 0; k < 8; ++k) FCC_STEP(tb + k, k)
        }

        // every ACTIVE step multiplies u by exp(-D9); absorb into c once.
        c += D9 * (float)(len - 1);

        float s = 0.f;
        #pragma unroll
        for (int mt = 0; mt < 2; ++mt)
            #pragma unroll
            for (int r = 0; r < 4; ++r) s += uprev[mt][r];
        s += __shfl_xor(s, 16);
        s += __shfl_xor(s, 32);
        if (lane < 16) wred[q][lane] = s;
        __syncthreads();
        if (tid < 16) {
            float tot = wred[0][tid] + wred[1][tid] + wred[2][tid] + wred[3][tid];
            fcc_out[(blockIdx.x << 4) + tid] = c + __logf(tot);
        }
    } else {
        // ================= FAC (1 wave per batch, no barriers) =================
        const int b   = ((blockIdx.x - 8) << 2) + q;
        const int len = ilen[b];
        const int tl  = tlen[b];
        const float* xb = x + (size_t)b * Tt * Nn;

        int   tgi[4];
        float st[4], ntr[4], bt[4];
        #pragma unroll
        for (int r = 0; r < 4; ++r) {
            const int s = (lane << 2) + r;
            const int tgv = targets[b * Ss + s];
            const int pg  = (s == 0) ? tgv : targets[b * Ss + s - 1];
            tgi[r] = tgv;
            st[r]  = trans[tgv * Nn + tgv];
            ntr[r] = trans[tgv * Nn + pg];
            bt[r]  = (s == 0) ? xb[tgv] : NEGF;
        }
        // em ring depth 8; em[(k-1)&7] = x[k] for k=1..8 (constant indices)
        float em[8][4];
        #pragma unroll
        for (int k = 1; k <= 8; ++k) {
            int tt = k; if (tt > Tt - 1) tt = Tt - 1;
            const float* xrow = xb + (size_t)tt * Nn;
            em[(k - 1) & 7][0] = xrow[tgi[0]];
            em[(k - 1) & 7][1] = xrow[tgi[1]];
            em[(k - 1) & 7][2] = xrow[tgi[2]];
            em[(k - 1) & 7][3] = xrow[tgi[3]];
        }

        #pragma unroll
        for (int k = 1; k < 8; ++k) FAC_STEP(k, k)
        for (int tb = 8; tb < Tt; tb += 8) {
            #pragma unroll
            for (int k = 0; k < 8; ++k) FAC_STEP(tb + k, k)
        }

        #pragma unroll
        for (int r = 0; r < 4; ++r)
            if ((lane << 2) + r == tl - 1) fac_out[b] = bt[r];
    }
}

__global__ __launch_bounds__(128) void reduce_kernel(const float* __restrict__ fcc,
                                                     const float* __restrict__ fac,
                                                     float* __restrict__ out) {
    __shared__ float r2[2];
    int tid = threadIdx.x;
    float v = fcc[tid] - fac[tid];
    #pragma unroll
    for (int o = 32; o > 0; o >>= 1) v += __shfl_xor(v, o);
    if ((tid & 63) == 0) r2[tid >> 6] = v;
    __syncthreads();
    if (tid == 0) out[0] = (r2[0] + r2[1]) * (1.0f / Bb);
}

extern "C" void kernel_launch(void* const* d_in, const int* in_sizes, int n_in,
                              void* d_out, int out_size, void* d_ws, size_t ws_size,
                              hipStream_t stream) {
    const float* trans   = (const float*)d_in[0];
    const float* x       = (const float*)d_in[1];
    const int*   targets = (const int*)d_in[2];
    const int*   ilen    = (const int*)d_in[3];
    const int*   tlen    = (const int*)d_in[4];
    float* out = (float*)d_out;

    float* fcc = (float*)d_ws;       // B floats
    float* fac = fcc + Bb;           // B floats

    asg_main<<<8 + Bb / 4, 256, 0, stream>>>(trans, x, targets, ilen, tlen, fcc, fac);
    reduce_kernel<<<1, 128, 0, stream>>>(fcc, fac, out);
}